// Round 11
// baseline (1570.240 us; speedup 1.0000x reference)
//
#include <hip/hip_runtime.h>
#include <stdint.h>

#define GAS __attribute__((address_space(1)))
#define LAS __attribute__((address_space(3)))

typedef __bf16 bf16x8 __attribute__((ext_vector_type(8)));
typedef _Float16 f16x8 __attribute__((ext_vector_type(8)));
typedef float f32x4 __attribute__((ext_vector_type(4)));
typedef unsigned u32x4 __attribute__((ext_vector_type(4)));

__device__ __forceinline__ unsigned short f2bf(float f) {
  unsigned u = __float_as_uint(f);
  unsigned r = (u + 0x7FFFu + ((u >> 16) & 1u)) >> 16;
  return (unsigned short)r;
}

__device__ __forceinline__ float sigmoidf(float x) {
  return 1.f / (1.f + expf(-x));
}

// ---- MALL-coherent (agent) primitives ----------------------------------------
// tagged exchange store: dword = (tag<<16) | f16(v). No drain needed: consumer
// verifies tags on read and retries (drain-free publish).
__device__ __forceinline__ void stt(unsigned* p, unsigned tag, float v) {
  _Float16 h = (_Float16)v;
  unsigned d = (tag << 16) | (unsigned)__builtin_bit_cast(unsigned short, h);
  __hip_atomic_store(p, d, __ATOMIC_RELAXED, __HIP_MEMORY_SCOPE_AGENT);
}
__device__ __forceinline__ void stf_mall(unsigned* p, unsigned v) {
  __hip_atomic_store(p, v, __ATOMIC_RELAXED, __HIP_MEMORY_SCOPE_AGENT);
}
__device__ __forceinline__ unsigned ldf_mall(const unsigned* p) {
  return __hip_atomic_load(p, __ATOMIC_RELAXED, __HIP_MEMORY_SCOPE_AGENT);
}
// 16B MALL-coherent load, compile-time offset; IN FLIGHT until vmcnt(0)!
template <int OFF>
__device__ __forceinline__ u32x4 ld4c(const unsigned* p) {
  u32x4 r;
  asm volatile("global_load_dwordx4 %0, %1, off offset:%2 sc0 sc1"
               : "=v"(r) : "v"(p), "n"(OFF) : "memory");
  return r;
}

// ---------------- gather: x_bf16 [4096,512] from seq; word_emb f32 [64,512] ----
__global__ __launch_bounds__(128) void k_gather(
    const float* __restrict__ emb, const int* __restrict__ seq,
    const int* __restrict__ word, unsigned short* __restrict__ xbf,
    float* __restrict__ wemb) {
  int row = blockIdx.x;
  int tid = threadIdx.x;
  if (row < 4096) {
    const float* src = emb + (size_t)seq[row] * 512;
    unsigned short* dst = xbf + (size_t)row * 512;
    for (int e = tid; e < 512; e += 128) dst[e] = f2bf(src[e]);
  } else {
    int b = row - 4096;
    const float* src = emb + (size_t)word[b] * 512;
    float* dst = wemb + (size_t)b * 512;
    for (int e = tid; e < 512; e += 128) dst[e] = src[e];
  }
}

// ---------------- weight conversion: wih_bf [1536,512], dec_bf [32000,512] ----
__global__ __launch_bounds__(128) void k_conv(
    const float* __restrict__ Wih, const float* __restrict__ decW,
    unsigned short* __restrict__ wih_bf, unsigned short* __restrict__ dec_bf) {
  int row = blockIdx.x;
  int tid = threadIdx.x;
  if (row < 1536) {
    const float* s = Wih + (size_t)row * 512;
    unsigned short* d = wih_bf + (size_t)row * 512;
    for (int e = tid; e < 512; e += 128) d[e] = f2bf(s[e]);
  } else {
    int o = row - 1536;
    const float* s = decW + (size_t)o * 512;
    unsigned short* d = dec_bf + (size_t)o * 512;
    for (int e = tid; e < 512; e += 128) d[e] = f2bf(s[e]);
  }
}

// ---------------- step-invariant gate preactivations from word_emb ------------
__global__ __launch_bounds__(256) void k_pre(
    const float* __restrict__ ztW, const float* __restrict__ ztb,
    const float* __restrict__ rtW, const float* __restrict__ rtb,
    const float* __restrict__ wemb, float* __restrict__ ztp,
    float* __restrict__ rtp) {
  int idx = blockIdx.x * 256 + threadIdx.x;
  int b = idx >> 10, o = idx & 1023;
  const float4* we = (const float4*)(wemb + (size_t)b * 512);
  const float4* wr;
  float acc;
  if (o < 512) { wr = (const float4*)(ztW + (size_t)o * 1024); acc = ztb[o]; }
  else { wr = (const float4*)(rtW + (size_t)(o - 512) * 1024); acc = rtb[o - 512]; }
  for (int c = 0; c < 128; ++c) {
    float4 w = wr[c], e = we[c];
    acc += w.x * e.x + w.y * e.y + w.z * e.z + w.w * e.w;
  }
  if (o < 512) ztp[(size_t)b * 512 + o] = acc;
  else rtp[(size_t)b * 512 + (o - 512)] = acc;
}

// ---------------- bf16 GEMM, C[m,n] = sum_k A[m,k]*B[n,k] + bias[n] ----------
__global__ __launch_bounds__(256) void k_gemm_bt(
    const unsigned short* __restrict__ A, const unsigned short* __restrict__ B,
    float* __restrict__ C, const float* __restrict__ bias,
    int M, int N, int K) {
  __shared__ __align__(16) unsigned short As[128 * 32];
  __shared__ __align__(16) unsigned short Bs[128 * 32];
  int nt = N >> 7;
  int nwg = gridDim.x;
  int bid = blockIdx.x;
  int swz = (bid & 7) * (nwg >> 3) + (bid >> 3);  // XCD swizzle (nwg % 8 == 0)
  int m0 = (swz / nt) << 7, n0 = (swz % nt) << 7;
  int tid = threadIdx.x;
  int l = tid & 63, w = tid >> 6;
  int wr = w >> 1, wc = w & 1;
  int lr = l & 15, lk = l >> 4;
  f32x4 acc[4][4] = {};
  for (int k0 = 0; k0 < K; k0 += 32) {
#pragma unroll
    for (int i = 0; i < 2; ++i) {
      int c = w * 2 + i;
      int off = c * 1024 + l * 16;
      int row = off >> 6, kb = off & 63;
      const char* ga = (const char*)A + ((size_t)(m0 + row) * K + k0) * 2 + kb;
      const char* gb = (const char*)B + ((size_t)(n0 + row) * K + k0) * 2 + kb;
      __builtin_amdgcn_global_load_lds((const GAS void*)ga,
                                       (LAS void*)((char*)As + c * 1024), 16, 0, 0);
      __builtin_amdgcn_global_load_lds((const GAS void*)gb,
                                       (LAS void*)((char*)Bs + c * 1024), 16, 0, 0);
    }
    asm volatile("s_waitcnt vmcnt(0)" ::: "memory");
    __syncthreads();
    bf16x8 af[4], bfr[4];
#pragma unroll
    for (int i = 0; i < 4; ++i)
      af[i] = *(const bf16x8*)&As[(wr * 64 + i * 16 + lr) * 32 + lk * 8];
#pragma unroll
    for (int i = 0; i < 4; ++i)
      bfr[i] = *(const bf16x8*)&Bs[(wc * 64 + i * 16 + lr) * 32 + lk * 8];
#pragma unroll
    for (int i = 0; i < 4; ++i)
#pragma unroll
      for (int jj = 0; jj < 4; ++jj)
        acc[i][jj] = __builtin_amdgcn_mfma_f32_16x16x32_bf16(af[i], bfr[jj], acc[i][jj], 0, 0, 0);
    __syncthreads();
  }
#pragma unroll
  for (int jj = 0; jj < 4; ++jj) {
    int col = n0 + wc * 64 + jj * 16 + lr;
    float bv = bias ? bias[col] : 0.f;
#pragma unroll
    for (int i = 0; i < 4; ++i) {
      int rb = m0 + wr * 64 + i * 16 + lk * 4;
#pragma unroll
      for (int q = 0; q < 4; ++q)
        C[(size_t)(rb + q) * N + col] = acc[i][jj][q] + bv;
    }
  }
}

// ---------------- recurrence: 32 wgs, column ownership, LDS weights -----------
// r9 structure + DRAIN-FREE publish: exchange dwords are (tag<<16)|f16; the
// producer never waits on store acks. Flags (64B-spread, per (wg,band)) are a
// cheap "probably ready" hint; the consumer loads data once and verifies tags,
// retrying only for straggler stores. Saves one full MALL transit per hop.
struct RnnP {
  const float *Whh, *ztW, *rtW, *htW;
  const float *gi, *ztp, *rtp, *wemb, *inith, *bhh, *htb;
  unsigned *hcurT, *hgruT, *rwT;  // u32[64][512] tagged exchange
  unsigned short *outsb;
  float *hfin;
  unsigned *flags;  // 128 slots (g*4+w), 64B apart
};

__device__ __forceinline__ void poll_band(const unsigned* flags, int w, int l,
                                          unsigned tgt) {
  const unsigned* fp = flags + ((size_t)((l & 31) * 4 + w)) * 16;
  for (;;) {
    unsigned v = ldf_mall(fp);
    if (__all((int)(v >= tgt))) break;
  }
}

// acc[n] += A[64,512] (band rows 16w..16w+16) x WL-slice; A is tagged u32.
// Loads all 32 fragments, verifies tags, retries if any store hasn't landed.
template <int NT>
__device__ __forceinline__ void mm_tag(f32x4* acc, const unsigned* At,
                                       const _Float16* WLrow, unsigned tag,
                                       int w, int lr, int lk) {
  u32x4 raw[32];
  const unsigned* arow = At + ((size_t)(16 * w + lr)) * 512 + lk * 8;
  const unsigned texp = tag << 16;
  for (;;) {
#define LD2(c) \
    raw[2 * (c)] = ld4c<(c) * 128>(arow); \
    raw[2 * (c) + 1] = ld4c<(c) * 128 + 16>(arow);
    LD2(0) LD2(1) LD2(2) LD2(3) LD2(4) LD2(5) LD2(6) LD2(7)
    LD2(8) LD2(9) LD2(10) LD2(11) LD2(12) LD2(13) LD2(14) LD2(15)
#undef LD2
    asm volatile("s_waitcnt vmcnt(0)" ::: "memory");
    __builtin_amdgcn_sched_barrier(0);
    unsigned bad = 0;
#pragma unroll
    for (int i = 0; i < 32; ++i) {
      u32x4 v = raw[i];
      bad |= (v.x ^ texp) | (v.y ^ texp) | (v.z ^ texp) | (v.w ^ texp);
    }
    if (__all((int)((bad >> 16) == 0u))) break;
  }
  __builtin_amdgcn_sched_barrier(0);
#pragma unroll
  for (int c = 0; c < 16; ++c) {
    unsigned p0 = __builtin_amdgcn_perm(raw[2 * c].y, raw[2 * c].x, 0x05040100);
    unsigned p1 = __builtin_amdgcn_perm(raw[2 * c].w, raw[2 * c].z, 0x05040100);
    unsigned p2 = __builtin_amdgcn_perm(raw[2 * c + 1].y, raw[2 * c + 1].x, 0x05040100);
    unsigned p3 = __builtin_amdgcn_perm(raw[2 * c + 1].w, raw[2 * c + 1].z, 0x05040100);
    u32x4 pk = {p0, p1, p2, p3};
    f16x8 a = __builtin_bit_cast(f16x8, pk);
#pragma unroll
    for (int n = 0; n < NT; ++n) {
      f16x8 bb = *(const f16x8*)(WLrow + (n * 16 + lr) * 520 + c * 32 + lk * 8);
      acc[n] = __builtin_amdgcn_mfma_f32_16x16x32_f16(a, bb, acc[n], 0, 0, 0);
    }
  }
}

__global__ __launch_bounds__(256) void k_rnn7(RnnP p) {
  const int g = blockIdx.x, tid = threadIdx.x;
  const int w = tid >> 6, l = tid & 63;
  const int lr = l & 15, lk = l >> 4;
  unsigned* myflag = p.flags + ((size_t)(g * 4 + w)) * 16;
  // 112 rows x 520 halfs (512 + 8 pad)
  __shared__ _Float16 WL[112 * 520];
  for (int idx = tid; idx < 112 * 512; idx += 256) {
    int rr = idx >> 9, e = idx & 511;
    const float* src;
    if (rr < 48) {
      int gate = rr >> 4, i = rr & 15;
      src = p.Whh + ((size_t)(gate * 512 + g * 16 + i)) * 512 + e;
    } else if (rr < 96) {
      int r2 = rr - 48, gate = r2 >> 4, i = r2 & 15;
      const float* base = gate == 0 ? p.ztW : (gate == 1 ? p.rtW : p.htW);
      src = base + ((size_t)(g * 16 + i)) * 1024 + 512 + e;
    } else {
      int i = rr - 96;
      src = p.htW + ((size_t)(g * 16 + i)) * 1024 + e;
    }
    WL[rr * 520 + e] = (_Float16)(*src);
  }
  // ---- per-lane owned coordinates: col j, batch rows brow..brow+3 ----
  const int j = g * 16 + lr;
  const int brow = 16 * w + lk * 4;
  f32x4 hprev, zp, rp, wev;
#pragma unroll
  for (int q = 0; q < 4; ++q) {
    int b = brow + q;
    hprev[q] = p.inith[(size_t)b * 512 + j];
    zp[q] = p.ztp[(size_t)b * 512 + j];
    rp[q] = p.rtp[(size_t)b * 512 + j];
    wev[q] = p.wemb[(size_t)b * 512 + j];
    stt(&p.hcurT[(size_t)b * 512 + j], 3u, hprev[q]);  // initial h, tag 3
  }
  const float br = p.bhh[j], bz = p.bhh[512 + j], bn = p.bhh[1024 + j];
  const float bht = p.htb[j];
  float gir[12];
#pragma unroll
  for (int q = 0; q < 4; ++q) {
    const float* git = p.gi + (size_t)(brow + q) * 1536;
    gir[q * 3 + 0] = git[j];
    gir[q * 3 + 1] = git[512 + j];
    gir[q * 3 + 2] = git[1024 + j];
  }
  __syncthreads();  // WL ready (also naturally spaces initial stores)
  if (l == 0) stf_mall(myflag, 3u);

  for (int t = 0; t < 64; ++t) {
    const unsigned base = 3u * (unsigned)t;
    // ---- phase 1: gates r,z,n ; h_gru ----
    poll_band(p.flags, w, l, base + 3);
    f32x4 acc1[3] = {};
    mm_tag<3>(acc1, p.hcurT, &WL[0], base + 3, w, lr, lk);
    f32x4 hg;
#pragma unroll
    for (int q = 0; q < 4; ++q) {
      int b = brow + q;
      float r = sigmoidf(gir[q * 3 + 0] + br + acc1[0][q]);
      float z = sigmoidf(gir[q * 3 + 1] + bz + acc1[1][q]);
      float n = tanhf(gir[q * 3 + 2] + r * (acc1[2][q] + bn));
      float hgq = (1.f - z) * n + z * hprev[q];
      hg[q] = hgq;
      stt(&p.hgruT[(size_t)b * 512 + j], base + 4, hgq);  // drain-free publish
    }
    if (l == 0) stf_mall(myflag, base + 4);
    // deferred: outsb stores + next-step gi prefetch (off the critical path)
#pragma unroll
    for (int q = 0; q < 4; ++q)
      p.outsb[((size_t)t * 64 + brow + q) * 512 + j] = f2bf(hg[q]);
    if (t < 63) {
      const float* git = p.gi + (size_t)(t + 1) * 64 * 1536;
#pragma unroll
      for (int q = 0; q < 4; ++q) {
        const float* gb = git + (size_t)(brow + q) * 1536;
        gir[q * 3 + 0] = gb[j];
        gir[q * 3 + 1] = gb[512 + j];
        gir[q * 3 + 2] = gb[1024 + j];
      }
    }
    // ---- phase 2: zt, rt, htB ----
    poll_band(p.flags, w, l, base + 4);
    f32x4 acc2[3] = {};
    mm_tag<3>(acc2, p.hgruT, &WL[48 * 520], base + 4, w, lr, lk);
    f32x4 zt, htB;
#pragma unroll
    for (int q = 0; q < 4; ++q) {
      int b = brow + q;
      float ztq = sigmoidf(zp[q] + acc2[0][q]);
      float rtq = sigmoidf(rp[q] + acc2[1][q]);
      zt[q] = ztq;
      htB[q] = acc2[2][q];
      stt(&p.rwT[(size_t)b * 512 + j], base + 5, rtq * wev[q]);
    }
    if (l == 0) stf_mall(myflag, base + 5);
    // ---- phase 3: htA ; h_new ----
    poll_band(p.flags, w, l, base + 5);
    f32x4 acc3[1] = {};
    mm_tag<1>(acc3, p.rwT, &WL[96 * 520], base + 5, w, lr, lk);
#pragma unroll
    for (int q = 0; q < 4; ++q) {
      int b = brow + q;
      float htl = tanhf(acc3[0][q] + htB[q] + bht);
      float hn2 = (1.f - zt[q]) * hg[q] + zt[q] * htl;
      hprev[q] = hn2;
      if (t < 63) stt(&p.hcurT[(size_t)b * 512 + j], base + 6, hn2);
      else p.hfin[(size_t)b * 512 + j] = hn2;
    }
    if (t < 63) {
      if (l == 0) stf_mall(myflag, base + 6);
    }
  }
}

extern "C" void kernel_launch(void* const* d_in, const int* in_sizes, int n_in,
                              void* d_out, int out_size, void* d_ws, size_t ws_size,
                              hipStream_t stream) {
  const float* emb   = (const float*)d_in[0];
  const float* Wih   = (const float*)d_in[1];
  const float* Whh   = (const float*)d_in[2];
  const float* bih   = (const float*)d_in[3];
  const float* bhh   = (const float*)d_in[4];
  const float* ztW   = (const float*)d_in[5];
  const float* ztb   = (const float*)d_in[6];
  const float* rtW   = (const float*)d_in[7];
  const float* rtb   = (const float*)d_in[8];
  const float* htW   = (const float*)d_in[9];
  const float* htb   = (const float*)d_in[10];
  const float* decW  = (const float*)d_in[11];
  const float* decb  = (const float*)d_in[12];
  const float* inith = (const float*)d_in[13];
  const int* word    = (const int*)d_in[14];
  const int* seq     = (const int*)d_in[15];
  float* out = (float*)d_out;

  char* ws = (char*)d_ws;
  size_t off = 0;
  auto alloc = [&](size_t bytes) {
    size_t o = off;
    off += (bytes + 255) & ~(size_t)255;
    return o;
  };
  unsigned short* xbf   = (unsigned short*)(ws + alloc(4096ull * 512 * 2));
  unsigned short* wihbf = (unsigned short*)(ws + alloc(1536ull * 512 * 2));
  unsigned short* decbf = (unsigned short*)(ws + alloc(32000ull * 512 * 2));
  float* wemb           = (float*)(ws + alloc(64ull * 512 * 4));
  float* ztp            = (float*)(ws + alloc(64ull * 512 * 4));
  float* rtp            = (float*)(ws + alloc(64ull * 512 * 4));
  float* gi             = (float*)(ws + alloc(4096ull * 1536 * 4));
  unsigned short* outsb = (unsigned short*)(ws + alloc(4096ull * 512 * 2));
  unsigned* hcurT       = (unsigned*)(ws + alloc(64ull * 512 * 4));
  unsigned* hgruT       = (unsigned*)(ws + alloc(64ull * 512 * 4));
  unsigned* rwT         = (unsigned*)(ws + alloc(64ull * 512 * 4));
  unsigned* flags       = (unsigned*)(ws + alloc(128 * 64));

  hipLaunchKernelGGL(k_gather, dim3(4160), dim3(128), 0, stream,
                     emb, seq, word, xbf, wemb);
  hipLaunchKernelGGL(k_conv, dim3(33536), dim3(128), 0, stream,
                     Wih, decW, wihbf, decbf);
  hipLaunchKernelGGL(k_pre, dim3(256), dim3(256), 0, stream,
                     ztW, ztb, rtW, rtb, wemb, ztp, rtp);
  hipLaunchKernelGGL(k_gemm_bt, dim3(384), dim3(256), 0, stream,
                     xbf, wihbf, gi, bih, 4096, 1536, 512);
  // reset exchange tags (hcurT/hgruT/rwT contiguous) + flags — replay-safe
  hipMemsetAsync(hcurT, 0, 3ull * 64 * 512 * 4, stream);
  hipMemsetAsync(flags, 0, 128 * 64, stream);
  RnnP p{Whh, ztW, rtW, htW, gi, ztp, rtp, wemb, inith, bhh, htb,
         hcurT, hgruT, rwT, outsb, out + 4096ull * 32000, flags};
  hipLaunchKernelGGL(k_rnn7, dim3(32), dim3(256), 0, stream, p);
  hipLaunchKernelGGL(k_gemm_bt, dim3(8000), dim3(256), 0, stream,
                     outsb, decbf, out, decb, 4096, 32000, 512);
}

// Round 12
// 1408.741 us; speedup vs baseline: 1.1146x; 1.1146x over previous
//
#include <hip/hip_runtime.h>
#include <stdint.h>

#define GAS __attribute__((address_space(1)))
#define LAS __attribute__((address_space(3)))

typedef __bf16 bf16x8 __attribute__((ext_vector_type(8)));
typedef _Float16 f16x8 __attribute__((ext_vector_type(8)));
typedef float f32x4 __attribute__((ext_vector_type(4)));
typedef unsigned u32x4 __attribute__((ext_vector_type(4)));

__device__ __forceinline__ unsigned short f2bf(float f) {
  unsigned u = __float_as_uint(f);
  unsigned r = (u + 0x7FFFu + ((u >> 16) & 1u)) >> 16;
  return (unsigned short)r;
}

__device__ __forceinline__ float sigmoidf(float x) {
  return 1.f / (1.f + expf(-x));
}

// ---- MALL-coherent (agent) exchange primitives (verified r3/r4/r9) -----------
__device__ __forceinline__ void st2c(_Float16* p, _Float16 v) {
  unsigned short u = __builtin_bit_cast(unsigned short, v);
  __hip_atomic_store((unsigned short*)p, u, __ATOMIC_RELAXED, __HIP_MEMORY_SCOPE_AGENT);
}
__device__ __forceinline__ void stf_mall(unsigned* p, unsigned v) {
  __hip_atomic_store(p, v, __ATOMIC_RELAXED, __HIP_MEMORY_SCOPE_AGENT);
}
__device__ __forceinline__ unsigned ldf_mall(const unsigned* p) {
  return __hip_atomic_load(p, __ATOMIC_RELAXED, __HIP_MEMORY_SCOPE_AGENT);
}
// 16B MALL-coherent load; result IN FLIGHT until s_waitcnt vmcnt(0)!
template <int OFF>
__device__ __forceinline__ f16x8 ldh8_mall(const _Float16* p) {
  u32x4 r;
  asm volatile("global_load_dwordx4 %0, %1, off offset:%2 sc0 sc1"
               : "=v"(r) : "v"(p), "n"(OFF) : "memory");
  return __builtin_bit_cast(f16x8, r);
}

// ---------------- gather: x_bf16 [4096,512] from seq; word_emb f32 [64,512] ----
__global__ __launch_bounds__(128) void k_gather(
    const float* __restrict__ emb, const int* __restrict__ seq,
    const int* __restrict__ word, unsigned short* __restrict__ xbf,
    float* __restrict__ wemb) {
  int row = blockIdx.x;
  int tid = threadIdx.x;
  if (row < 4096) {
    const float* src = emb + (size_t)seq[row] * 512;
    unsigned short* dst = xbf + (size_t)row * 512;
    for (int e = tid; e < 512; e += 128) dst[e] = f2bf(src[e]);
  } else {
    int b = row - 4096;
    const float* src = emb + (size_t)word[b] * 512;
    float* dst = wemb + (size_t)b * 512;
    for (int e = tid; e < 512; e += 128) dst[e] = src[e];
  }
}

// ---------------- weight conversion: wih_bf [1536,512], dec_bf [32000,512] ----
__global__ __launch_bounds__(128) void k_conv(
    const float* __restrict__ Wih, const float* __restrict__ decW,
    unsigned short* __restrict__ wih_bf, unsigned short* __restrict__ dec_bf) {
  int row = blockIdx.x;
  int tid = threadIdx.x;
  if (row < 1536) {
    const float* s = Wih + (size_t)row * 512;
    unsigned short* d = wih_bf + (size_t)row * 512;
    for (int e = tid; e < 512; e += 128) d[e] = f2bf(s[e]);
  } else {
    int o = row - 1536;
    const float* s = decW + (size_t)o * 512;
    unsigned short* d = dec_bf + (size_t)o * 512;
    for (int e = tid; e < 512; e += 128) d[e] = f2bf(s[e]);
  }
}

// ---------------- step-invariant gate preactivations from word_emb ------------
__global__ __launch_bounds__(256) void k_pre(
    const float* __restrict__ ztW, const float* __restrict__ ztb,
    const float* __restrict__ rtW, const float* __restrict__ rtb,
    const float* __restrict__ wemb, float* __restrict__ ztp,
    float* __restrict__ rtp) {
  int idx = blockIdx.x * 256 + threadIdx.x;
  int b = idx >> 10, o = idx & 1023;
  const float4* we = (const float4*)(wemb + (size_t)b * 512);
  const float4* wr;
  float acc;
  if (o < 512) { wr = (const float4*)(ztW + (size_t)o * 1024); acc = ztb[o]; }
  else { wr = (const float4*)(rtW + (size_t)(o - 512) * 1024); acc = rtb[o - 512]; }
  for (int c = 0; c < 128; ++c) {
    float4 w = wr[c], e = we[c];
    acc += w.x * e.x + w.y * e.y + w.z * e.z + w.w * e.w;
  }
  if (o < 512) ztp[(size_t)b * 512 + o] = acc;
  else rtp[(size_t)b * 512 + (o - 512)] = acc;
}

// ---------------- bf16 GEMM, C[m,n] = sum_k A[m,k]*B[n,k] + bias[n] ----------
__global__ __launch_bounds__(256) void k_gemm_bt(
    const unsigned short* __restrict__ A, const unsigned short* __restrict__ B,
    float* __restrict__ C, const float* __restrict__ bias,
    int M, int N, int K) {
  __shared__ __align__(16) unsigned short As[128 * 32];
  __shared__ __align__(16) unsigned short Bs[128 * 32];
  int nt = N >> 7;
  int nwg = gridDim.x;
  int bid = blockIdx.x;
  int swz = (bid & 7) * (nwg >> 3) + (bid >> 3);  // XCD swizzle (nwg % 8 == 0)
  int m0 = (swz / nt) << 7, n0 = (swz % nt) << 7;
  int tid = threadIdx.x;
  int l = tid & 63, w = tid >> 6;
  int wr = w >> 1, wc = w & 1;
  int lr = l & 15, lk = l >> 4;
  f32x4 acc[4][4] = {};
  for (int k0 = 0; k0 < K; k0 += 32) {
#pragma unroll
    for (int i = 0; i < 2; ++i) {
      int c = w * 2 + i;
      int off = c * 1024 + l * 16;
      int row = off >> 6, kb = off & 63;
      const char* ga = (const char*)A + ((size_t)(m0 + row) * K + k0) * 2 + kb;
      const char* gb = (const char*)B + ((size_t)(n0 + row) * K + k0) * 2 + kb;
      __builtin_amdgcn_global_load_lds((const GAS void*)ga,
                                       (LAS void*)((char*)As + c * 1024), 16, 0, 0);
      __builtin_amdgcn_global_load_lds((const GAS void*)gb,
                                       (LAS void*)((char*)Bs + c * 1024), 16, 0, 0);
    }
    asm volatile("s_waitcnt vmcnt(0)" ::: "memory");
    __syncthreads();
    bf16x8 af[4], bfr[4];
#pragma unroll
    for (int i = 0; i < 4; ++i)
      af[i] = *(const bf16x8*)&As[(wr * 64 + i * 16 + lr) * 32 + lk * 8];
#pragma unroll
    for (int i = 0; i < 4; ++i)
      bfr[i] = *(const bf16x8*)&Bs[(wc * 64 + i * 16 + lr) * 32 + lk * 8];
#pragma unroll
    for (int i = 0; i < 4; ++i)
#pragma unroll
      for (int jj = 0; jj < 4; ++jj)
        acc[i][jj] = __builtin_amdgcn_mfma_f32_16x16x32_bf16(af[i], bfr[jj], acc[i][jj], 0, 0, 0);
    __syncthreads();
  }
#pragma unroll
  for (int jj = 0; jj < 4; ++jj) {
    int col = n0 + wc * 64 + jj * 16 + lr;
    float bv = bias ? bias[col] : 0.f;
#pragma unroll
    for (int i = 0; i < 4; ++i) {
      int rb = m0 + wr * 64 + i * 16 + lk * 4;
#pragma unroll
      for (int q = 0; q < 4; ++q)
        C[(size_t)(rb + q) * N + col] = acc[i][jj][q] + bv;
    }
  }
}

// ---------------- recurrence: 32 wgs, column ownership, LDS weights -----------
// r9 protocol (ack-then-flag, 64B-spread flags) + INCREMENTAL consumption:
// during the wait for straggler producers, already-published 32-col chunk
// pairs are loaded and folded (fixed fold order 0..15 -> deterministic).
struct RnnP {
  const float *Whh, *ztW, *rtW, *htW;
  const float *gi, *ztp, *rtp, *wemb, *inith, *bhh, *htb;
  _Float16 *hcurF, *hgruF, *rwF;
  unsigned short *outsb;
  float *hfin;
  unsigned *flags;  // 128 slots (g*4+w), 64B apart
};

// acc[n] += A[64,512] (band rows 16w..16w+16) x WL-slice, incremental:
// lane i<32 watches wg i's flag (band w). Pair p = wgs {2p,2p+1} = cols
// 32p..32p+32. Sweep: read flags -> ballot -> load newly-ready pairs
// (static unroll, uniform guards) -> fold contiguous prefix in order.
template <int NT>
__device__ __forceinline__ void mm_inc(f32x4* acc, const _Float16* A,
                                       const _Float16* WLrow, unsigned tgt,
                                       int w, int l, int lr, int lk,
                                       const unsigned* flags) {
  f16x8 af[16] = {};
  const _Float16* arow = A + ((size_t)(16 * w + lr)) * 512 + lk * 8;
  const unsigned* fp = flags + ((size_t)((l & 31) * 4 + w)) * 16;
  unsigned loaded = 0;  // even-bit space: bit 2p set when pair p loaded
  int folded = 0;       // pairs folded so far (contiguous prefix)
  while (folded < 16) {
    unsigned v = ldf_mall(fp);
    unsigned rm = (unsigned)__ballot((int)(v >= tgt));
    unsigned pr = rm & (rm >> 1) & 0x55555555u;  // bit 2p: pair p ready
    unsigned nl = pr & ~loaded;
    if (nl) {
#define LDP(p) if (nl & (1u << (2 * (p)))) af[p] = ldh8_mall<(p) * 64>(arow);
      LDP(0) LDP(1) LDP(2) LDP(3) LDP(4) LDP(5) LDP(6) LDP(7)
      LDP(8) LDP(9) LDP(10) LDP(11) LDP(12) LDP(13) LDP(14) LDP(15)
#undef LDP
      asm volatile("s_waitcnt vmcnt(0)" ::: "memory");
      __builtin_amdgcn_sched_barrier(0);
      loaded |= nl;
    }
#pragma unroll
    for (int p = 0; p < 16; ++p) {
      if (folded == p && ((loaded >> (2 * p)) & 1u)) {
#pragma unroll
        for (int n = 0; n < NT; ++n) {
          f16x8 bb = *(const f16x8*)(WLrow + (n * 16 + lr) * 520 + p * 32 + lk * 8);
          acc[n] = __builtin_amdgcn_mfma_f32_16x16x32_f16(af[p], bb, acc[n], 0, 0, 0);
        }
        folded = p + 1;
      }
    }
  }
}

__global__ __launch_bounds__(256) void k_rnn8(RnnP p) {
  const int g = blockIdx.x, tid = threadIdx.x;
  const int w = tid >> 6, l = tid & 63;
  const int lr = l & 15, lk = l >> 4;
  unsigned* myflag = p.flags + ((size_t)(g * 4 + w)) * 16;
  // 112 rows x 520 halfs (512 + 8 pad)
  __shared__ _Float16 WL[112 * 520];
  for (int idx = tid; idx < 112 * 512; idx += 256) {
    int rr = idx >> 9, e = idx & 511;
    const float* src;
    if (rr < 48) {
      int gate = rr >> 4, i = rr & 15;
      src = p.Whh + ((size_t)(gate * 512 + g * 16 + i)) * 512 + e;
    } else if (rr < 96) {
      int r2 = rr - 48, gate = r2 >> 4, i = r2 & 15;
      const float* base = gate == 0 ? p.ztW : (gate == 1 ? p.rtW : p.htW);
      src = base + ((size_t)(g * 16 + i)) * 1024 + 512 + e;
    } else {
      int i = rr - 96;
      src = p.htW + ((size_t)(g * 16 + i)) * 1024 + e;
    }
    WL[rr * 520 + e] = (_Float16)(*src);
  }
  // ---- per-lane owned coordinates: col j, batch rows brow..brow+3 ----
  const int j = g * 16 + lr;
  const int brow = 16 * w + lk * 4;
  f32x4 hprev, zp, rp, wev;
#pragma unroll
  for (int q = 0; q < 4; ++q) {
    int b = brow + q;
    hprev[q] = p.inith[(size_t)b * 512 + j];
    zp[q] = p.ztp[(size_t)b * 512 + j];
    rp[q] = p.rtp[(size_t)b * 512 + j];
    wev[q] = p.wemb[(size_t)b * 512 + j];
    st2c(&p.hcurF[(size_t)b * 512 + j], (_Float16)hprev[q]);
  }
  const float br = p.bhh[j], bz = p.bhh[512 + j], bn = p.bhh[1024 + j];
  const float bht = p.htb[j];
  float gir[12];
#pragma unroll
  for (int q = 0; q < 4; ++q) {
    const float* git = p.gi + (size_t)(brow + q) * 1536;
    gir[q * 3 + 0] = git[j];
    gir[q * 3 + 1] = git[512 + j];
    gir[q * 3 + 2] = git[1024 + j];
  }
  __syncthreads();  // WL ready; also drains all stores/loads above
  if (l == 0) stf_mall(myflag, 1u);

  for (int t = 0; t < 64; ++t) {
    const unsigned base = 3u * (unsigned)t;
    // ---- phase 1: gates r,z,n ; h_gru ----
    f32x4 acc1[3] = {};
    mm_inc<3>(acc1, p.hcurF, &WL[0], base + 1, w, l, lr, lk, p.flags);
    f32x4 hg;
#pragma unroll
    for (int q = 0; q < 4; ++q) {
      int b = brow + q;
      float r = sigmoidf(gir[q * 3 + 0] + br + acc1[0][q]);
      float z = sigmoidf(gir[q * 3 + 1] + bz + acc1[1][q]);
      float n = tanhf(gir[q * 3 + 2] + r * (acc1[2][q] + bn));
      float hgq = (1.f - z) * n + z * hprev[q];
      hg[q] = hgq;
      st2c(&p.hgruF[(size_t)b * 512 + j], (_Float16)hgq);
    }
    asm volatile("s_waitcnt vmcnt(0)" ::: "memory");
    if (l == 0) stf_mall(myflag, base + 2);
    // deferred: outsb stores + next-step gi prefetch (off the critical path)
#pragma unroll
    for (int q = 0; q < 4; ++q)
      p.outsb[((size_t)t * 64 + brow + q) * 512 + j] = f2bf(hg[q]);
    if (t < 63) {
      const float* git = p.gi + (size_t)(t + 1) * 64 * 1536;
#pragma unroll
      for (int q = 0; q < 4; ++q) {
        const float* gb = git + (size_t)(brow + q) * 1536;
        gir[q * 3 + 0] = gb[j];
        gir[q * 3 + 1] = gb[512 + j];
        gir[q * 3 + 2] = gb[1024 + j];
      }
    }
    // ---- phase 2: zt, rt, htB ----
    f32x4 acc2[3] = {};
    mm_inc<3>(acc2, p.hgruF, &WL[48 * 520], base + 2, w, l, lr, lk, p.flags);
    f32x4 zt, htB;
#pragma unroll
    for (int q = 0; q < 4; ++q) {
      int b = brow + q;
      float ztq = sigmoidf(zp[q] + acc2[0][q]);
      float rtq = sigmoidf(rp[q] + acc2[1][q]);
      zt[q] = ztq;
      htB[q] = acc2[2][q];
      st2c(&p.rwF[(size_t)b * 512 + j], (_Float16)(rtq * wev[q]));
    }
    asm volatile("s_waitcnt vmcnt(0)" ::: "memory");
    if (l == 0) stf_mall(myflag, base + 3);
    // ---- phase 3: htA ; h_new ----
    f32x4 acc3[1] = {};
    mm_inc<1>(acc3, p.rwF, &WL[96 * 520], base + 3, w, l, lr, lk, p.flags);
#pragma unroll
    for (int q = 0; q < 4; ++q) {
      int b = brow + q;
      float htl = tanhf(acc3[0][q] + htB[q] + bht);
      float hn2 = (1.f - zt[q]) * hg[q] + zt[q] * htl;
      hprev[q] = hn2;
      if (t < 63) st2c(&p.hcurF[(size_t)b * 512 + j], (_Float16)hn2);
      else p.hfin[(size_t)b * 512 + j] = hn2;
    }
    if (t < 63) {
      asm volatile("s_waitcnt vmcnt(0)" ::: "memory");
      if (l == 0) stf_mall(myflag, base + 4);
    }
  }
}

extern "C" void kernel_launch(void* const* d_in, const int* in_sizes, int n_in,
                              void* d_out, int out_size, void* d_ws, size_t ws_size,
                              hipStream_t stream) {
  const float* emb   = (const float*)d_in[0];
  const float* Wih   = (const float*)d_in[1];
  const float* Whh   = (const float*)d_in[2];
  const float* bih   = (const float*)d_in[3];
  const float* bhh   = (const float*)d_in[4];
  const float* ztW   = (const float*)d_in[5];
  const float* ztb   = (const float*)d_in[6];
  const float* rtW   = (const float*)d_in[7];
  const float* rtb   = (const float*)d_in[8];
  const float* htW   = (const float*)d_in[9];
  const float* htb   = (const float*)d_in[10];
  const float* decW  = (const float*)d_in[11];
  const float* decb  = (const float*)d_in[12];
  const float* inith = (const float*)d_in[13];
  const int* word    = (const int*)d_in[14];
  const int* seq     = (const int*)d_in[15];
  float* out = (float*)d_out;

  char* ws = (char*)d_ws;
  size_t off = 0;
  auto alloc = [&](size_t bytes) {
    size_t o = off;
    off += (bytes + 255) & ~(size_t)255;
    return o;
  };
  unsigned short* xbf   = (unsigned short*)(ws + alloc(4096ull * 512 * 2));
  unsigned short* wihbf = (unsigned short*)(ws + alloc(1536ull * 512 * 2));
  unsigned short* decbf = (unsigned short*)(ws + alloc(32000ull * 512 * 2));
  float* wemb           = (float*)(ws + alloc(64ull * 512 * 4));
  float* ztp            = (float*)(ws + alloc(64ull * 512 * 4));
  float* rtp            = (float*)(ws + alloc(64ull * 512 * 4));
  float* gi             = (float*)(ws + alloc(4096ull * 1536 * 4));
  unsigned short* outsb = (unsigned short*)(ws + alloc(4096ull * 512 * 2));
  _Float16* hcurF       = (_Float16*)(ws + alloc(64ull * 512 * 2));
  _Float16* hgruF       = (_Float16*)(ws + alloc(64ull * 512 * 2));
  _Float16* rwF         = (_Float16*)(ws + alloc(64ull * 512 * 2));
  unsigned* flags       = (unsigned*)(ws + alloc(128 * 64));

  hipLaunchKernelGGL(k_gather, dim3(4160), dim3(128), 0, stream,
                     emb, seq, word, xbf, wemb);
  hipLaunchKernelGGL(k_conv, dim3(33536), dim3(128), 0, stream,
                     Wih, decW, wihbf, decbf);
  hipLaunchKernelGGL(k_pre, dim3(256), dim3(256), 0, stream,
                     ztW, ztb, rtW, rtb, wemb, ztp, rtp);
  hipLaunchKernelGGL(k_gemm_bt, dim3(384), dim3(256), 0, stream,
                     xbf, wihbf, gi, bih, 4096, 1536, 512);
  hipMemsetAsync(flags, 0, 128 * 64, stream);
  RnnP p{Whh, ztW, rtW, htW, gi, ztp, rtp, wemb, inith, bhh, htb,
         hcurF, hgruF, rwF, outsb, out + 4096ull * 32000, flags};
  hipLaunchKernelGGL(k_rnn8, dim3(32), dim3(256), 0, stream, p);
  hipLaunchKernelGGL(k_gemm_bt, dim3(8000), dim3(256), 0, stream,
                     outsb, decbf, out, decb, 4096, 32000, 512);
}

// Round 13
// 1225.392 us; speedup vs baseline: 1.2814x; 1.1496x over previous
//
#include <hip/hip_runtime.h>
#include <stdint.h>

#define GAS __attribute__((address_space(1)))
#define LAS __attribute__((address_space(3)))

typedef __bf16 bf16x8 __attribute__((ext_vector_type(8)));
typedef _Float16 f16x8 __attribute__((ext_vector_type(8)));
typedef float f32x4 __attribute__((ext_vector_type(4)));
typedef unsigned u32x4 __attribute__((ext_vector_type(4)));

__device__ __forceinline__ unsigned short f2bf(float f) {
  unsigned u = __float_as_uint(f);
  unsigned r = (u + 0x7FFFu + ((u >> 16) & 1u)) >> 16;
  return (unsigned short)r;
}

__device__ __forceinline__ float sigmoidf(float x) {
  return 1.f / (1.f + expf(-x));
}

// ---- MALL-coherent (agent) exchange primitives (verified r3/r4/r9) -----------
__device__ __forceinline__ void st2c(_Float16* p, _Float16 v) {
  unsigned short u = __builtin_bit_cast(unsigned short, v);
  __hip_atomic_store((unsigned short*)p, u, __ATOMIC_RELAXED, __HIP_MEMORY_SCOPE_AGENT);
}
__device__ __forceinline__ void stf_mall(unsigned* p, unsigned v) {
  __hip_atomic_store(p, v, __ATOMIC_RELAXED, __HIP_MEMORY_SCOPE_AGENT);
}
__device__ __forceinline__ unsigned ldf_mall(const unsigned* p) {
  return __hip_atomic_load(p, __ATOMIC_RELAXED, __HIP_MEMORY_SCOPE_AGENT);
}
// 16B MALL-coherent load; result IN FLIGHT until s_waitcnt vmcnt(0)!
template <int OFF>
__device__ __forceinline__ f16x8 ldh8_mall(const _Float16* p) {
  u32x4 r;
  asm volatile("global_load_dwordx4 %0, %1, off offset:%2 sc0 sc1"
               : "=v"(r) : "v"(p), "n"(OFF) : "memory");
  return __builtin_bit_cast(f16x8, r);
}

// ---------------- gather: x_bf16 [4096,512] from seq; word_emb f32 [64,512] ----
__global__ __launch_bounds__(128) void k_gather(
    const float* __restrict__ emb, const int* __restrict__ seq,
    const int* __restrict__ word, unsigned short* __restrict__ xbf,
    float* __restrict__ wemb) {
  int row = blockIdx.x;
  int tid = threadIdx.x;
  if (row < 4096) {
    const float* src = emb + (size_t)seq[row] * 512;
    unsigned short* dst = xbf + (size_t)row * 512;
    for (int e = tid; e < 512; e += 128) dst[e] = f2bf(src[e]);
  } else {
    int b = row - 4096;
    const float* src = emb + (size_t)word[b] * 512;
    float* dst = wemb + (size_t)b * 512;
    for (int e = tid; e < 512; e += 128) dst[e] = src[e];
  }
}

// ---------------- weight conversion: wih_bf [1536,512], dec_bf [32000,512] ----
__global__ __launch_bounds__(128) void k_conv(
    const float* __restrict__ Wih, const float* __restrict__ decW,
    unsigned short* __restrict__ wih_bf, unsigned short* __restrict__ dec_bf) {
  int row = blockIdx.x;
  int tid = threadIdx.x;
  if (row < 1536) {
    const float* s = Wih + (size_t)row * 512;
    unsigned short* d = wih_bf + (size_t)row * 512;
    for (int e = tid; e < 512; e += 128) d[e] = f2bf(s[e]);
  } else {
    int o = row - 1536;
    const float* s = decW + (size_t)o * 512;
    unsigned short* d = dec_bf + (size_t)o * 512;
    for (int e = tid; e < 512; e += 128) d[e] = f2bf(s[e]);
  }
}

// ---------------- step-invariant gate preactivations from word_emb ------------
__global__ __launch_bounds__(256) void k_pre(
    const float* __restrict__ ztW, const float* __restrict__ ztb,
    const float* __restrict__ rtW, const float* __restrict__ rtb,
    const float* __restrict__ wemb, float* __restrict__ ztp,
    float* __restrict__ rtp) {
  int idx = blockIdx.x * 256 + threadIdx.x;
  int b = idx >> 10, o = idx & 1023;
  const float4* we = (const float4*)(wemb + (size_t)b * 512);
  const float4* wr;
  float acc;
  if (o < 512) { wr = (const float4*)(ztW + (size_t)o * 1024); acc = ztb[o]; }
  else { wr = (const float4*)(rtW + (size_t)(o - 512) * 1024); acc = rtb[o - 512]; }
  for (int c = 0; c < 128; ++c) {
    float4 w = wr[c], e = we[c];
    acc += w.x * e.x + w.y * e.y + w.z * e.z + w.w * e.w;
  }
  if (o < 512) ztp[(size_t)b * 512 + o] = acc;
  else rtp[(size_t)b * 512 + (o - 512)] = acc;
}

// ---------------- bf16 GEMM (gi only), BK=32 m97 structure --------------------
__global__ __launch_bounds__(256) void k_gemm_bt(
    const unsigned short* __restrict__ A, const unsigned short* __restrict__ B,
    float* __restrict__ C, const float* __restrict__ bias,
    int M, int N, int K) {
  __shared__ __align__(16) unsigned short As[128 * 32];
  __shared__ __align__(16) unsigned short Bs[128 * 32];
  int nt = N >> 7;
  int nwg = gridDim.x;
  int bid = blockIdx.x;
  int swz = (bid & 7) * (nwg >> 3) + (bid >> 3);  // XCD swizzle (nwg % 8 == 0)
  int m0 = (swz / nt) << 7, n0 = (swz % nt) << 7;
  int tid = threadIdx.x;
  int l = tid & 63, w = tid >> 6;
  int wr = w >> 1, wc = w & 1;
  int lr = l & 15, lk = l >> 4;
  f32x4 acc[4][4] = {};
  for (int k0 = 0; k0 < K; k0 += 32) {
#pragma unroll
    for (int i = 0; i < 2; ++i) {
      int c = w * 2 + i;
      int off = c * 1024 + l * 16;
      int row = off >> 6, kb = off & 63;
      const char* ga = (const char*)A + ((size_t)(m0 + row) * K + k0) * 2 + kb;
      const char* gb = (const char*)B + ((size_t)(n0 + row) * K + k0) * 2 + kb;
      __builtin_amdgcn_global_load_lds((const GAS void*)ga,
                                       (LAS void*)((char*)As + c * 1024), 16, 0, 0);
      __builtin_amdgcn_global_load_lds((const GAS void*)gb,
                                       (LAS void*)((char*)Bs + c * 1024), 16, 0, 0);
    }
    asm volatile("s_waitcnt vmcnt(0)" ::: "memory");
    __syncthreads();
    bf16x8 af[4], bfr[4];
#pragma unroll
    for (int i = 0; i < 4; ++i)
      af[i] = *(const bf16x8*)&As[(wr * 64 + i * 16 + lr) * 32 + lk * 8];
#pragma unroll
    for (int i = 0; i < 4; ++i)
      bfr[i] = *(const bf16x8*)&Bs[(wc * 64 + i * 16 + lr) * 32 + lk * 8];
#pragma unroll
    for (int i = 0; i < 4; ++i)
#pragma unroll
      for (int jj = 0; jj < 4; ++jj)
        acc[i][jj] = __builtin_amdgcn_mfma_f32_16x16x32_bf16(af[i], bfr[jj], acc[i][jj], 0, 0, 0);
    __syncthreads();
  }
#pragma unroll
  for (int jj = 0; jj < 4; ++jj) {
    int col = n0 + wc * 64 + jj * 16 + lr;
    float bv = bias ? bias[col] : 0.f;
#pragma unroll
    for (int i = 0; i < 4; ++i) {
      int rb = m0 + wr * 64 + i * 16 + lk * 4;
#pragma unroll
      for (int q = 0; q < 4; ++q)
        C[(size_t)(rb + q) * N + col] = acc[i][jj][q] + bv;
    }
  }
}

// ---------------- decode GEMM: M=4096 N=32000 K=512, BK=64, swizzled LDS ------
// T2 XOR-swizzle via pre-swizzled global source (rule #21): LDS dest linear,
// source byte-offset and ds_read both XOR ((row&7)<<4). Epilogue staged via
// LDS -> 512B-contiguous row writes.
__global__ __launch_bounds__(256) void k_dec(
    const unsigned short* __restrict__ A, const unsigned short* __restrict__ B,
    float* __restrict__ C, const float* __restrict__ bias) {
  __shared__ __align__(16) char LSD[64 * 132 * 4];     // 33792 B
  unsigned short* As = (unsigned short*)LSD;            // [128][64] bf16, linear
  unsigned short* Bs = (unsigned short*)(LSD + 16384);  // [128][64]
  float* Cst = (float*)LSD;                             // [64][132] f32 (reuse)
  const int nt = 250;
  int nwg = gridDim.x;  // 8000, %8==0
  int bid = blockIdx.x;
  int swz = (bid & 7) * (nwg >> 3) + (bid >> 3);
  int m0 = (swz / nt) << 7, n0 = (swz % nt) << 7;
  int tid = threadIdx.x;
  int l = tid & 63, w = tid >> 6;
  int wr = w >> 1, wc = w & 1;
  int lr = l & 15, lk = l >> 4;
  // lane's swizzled byte-offset within the 128B k-row: slot l%8, row&7 = l/8
  int srcswz = 16 * ((l & 7) ^ (l >> 3));
  f32x4 acc[4][4] = {};
  for (int k0 = 0; k0 < 512; k0 += 64) {
#pragma unroll
    for (int c = 0; c < 4; ++c) {
      int row = (w * 4 + c) * 8 + (l >> 3);
      const char* ga = (const char*)A + ((size_t)(m0 + row) * 512 + k0) * 2 + srcswz;
      const char* gb = (const char*)B + ((size_t)(n0 + row) * 512 + k0) * 2 + srcswz;
      __builtin_amdgcn_global_load_lds((const GAS void*)ga,
          (LAS void*)((char*)As + (w * 4 + c) * 1024), 16, 0, 0);
      __builtin_amdgcn_global_load_lds((const GAS void*)gb,
          (LAS void*)((char*)Bs + (w * 4 + c) * 1024), 16, 0, 0);
    }
    asm volatile("s_waitcnt vmcnt(0)" ::: "memory");
    __syncthreads();
#pragma unroll
    for (int h = 0; h < 2; ++h) {
      bf16x8 af[4], bfr[4];
#pragma unroll
      for (int i = 0; i < 4; ++i) {
        int rowa = wr * 64 + i * 16 + lr;
        int offa = rowa * 128 + ((h * 64 + lk * 16) ^ ((rowa & 7) << 4));
        af[i] = *(const bf16x8*)((const char*)As + offa);
        int rowb = wc * 64 + i * 16 + lr;
        int offb = rowb * 128 + ((h * 64 + lk * 16) ^ ((rowb & 7) << 4));
        bfr[i] = *(const bf16x8*)((const char*)Bs + offb);
      }
#pragma unroll
      for (int i = 0; i < 4; ++i)
#pragma unroll
        for (int jj = 0; jj < 4; ++jj)
          acc[i][jj] = __builtin_amdgcn_mfma_f32_16x16x32_bf16(af[i], bfr[jj], acc[i][jj], 0, 0, 0);
    }
    __syncthreads();
  }
  float bv[4];
#pragma unroll
  for (int jj = 0; jj < 4; ++jj) bv[jj] = bias[n0 + wc * 64 + jj * 16 + lr];
  // epilogue: 2 chunks of 64 rows; stage in LDS, write 512B-contiguous rows
#pragma unroll 1
  for (int ch = 0; ch < 2; ++ch) {
    __syncthreads();  // Cst region free (K-loop done / prev chunk copied)
    if (wr == ch) {
#pragma unroll
      for (int i = 0; i < 4; ++i)
#pragma unroll
        for (int jj = 0; jj < 4; ++jj)
#pragma unroll
          for (int q = 0; q < 4; ++q) {
            int rl = i * 16 + lk * 4 + q;
            int cl = wc * 64 + jj * 16 + lr;
            Cst[rl * 132 + cl] = acc[i][jj][q] + bv[jj];
          }
    }
    __syncthreads();
#pragma unroll
    for (int ps = 0; ps < 8; ++ps) {
      int flat = (ps * 256 + tid) * 4;  // 64 rows x 128 cols
      int rl = flat >> 7, cl = flat & 127;
      float4 v = *(const float4*)&Cst[rl * 132 + cl];
      *(float4*)&C[(size_t)(m0 + ch * 64 + rl) * 32000 + n0 + cl] = v;
    }
  }
}

// ---------------- recurrence: r9 champion, verbatim ---------------------------
struct RnnP {
  const float *Whh, *ztW, *rtW, *htW;
  const float *gi, *ztp, *rtp, *wemb, *inith, *bhh, *htb;
  _Float16 *hcurF, *hgruF, *rwF;
  unsigned short *outsb;
  float *hfin;
  unsigned *flags;  // 128 slots (g*4+w), 64B apart
};

__device__ __forceinline__ void poll_band(const unsigned* flags, int w, int l,
                                          unsigned tgt) {
  const unsigned* fp = flags + ((size_t)((l & 31) * 4 + w)) * 16;
  for (;;) {
    unsigned v = ldf_mall(fp);
    if (__all((int)(v >= tgt))) break;
  }
}

template <int NT>
__device__ __forceinline__ void mm_mall(f32x4* acc, const _Float16* A,
                                        const _Float16* WLrow, int w, int lr, int lk) {
  f16x8 af[16];
  const _Float16* arow = A + ((size_t)(16 * w + lr)) * 512 + lk * 8;
#define LDA(c) af[c] = ldh8_mall<(c) * 64>(arow);
  LDA(0) LDA(1) LDA(2) LDA(3) LDA(4) LDA(5) LDA(6) LDA(7)
  LDA(8) LDA(9) LDA(10) LDA(11) LDA(12) LDA(13) LDA(14) LDA(15)
#undef LDA
  asm volatile("s_waitcnt vmcnt(0)" ::: "memory");
  __builtin_amdgcn_sched_barrier(0);
#pragma unroll
  for (int c = 0; c < 16; ++c) {
#pragma unroll
    for (int n = 0; n < NT; ++n) {
      f16x8 bb = *(const f16x8*)(WLrow + (n * 16 + lr) * 520 + c * 32 + lk * 8);
      acc[n] = __builtin_amdgcn_mfma_f32_16x16x32_f16(af[c], bb, acc[n], 0, 0, 0);
    }
  }
}

__global__ __launch_bounds__(256) void k_rnn6(RnnP p) {
  const int g = blockIdx.x, tid = threadIdx.x;
  const int w = tid >> 6, l = tid & 63;
  const int lr = l & 15, lk = l >> 4;
  unsigned* myflag = p.flags + ((size_t)(g * 4 + w)) * 16;
  __shared__ _Float16 WL[112 * 520];
  for (int idx = tid; idx < 112 * 512; idx += 256) {
    int rr = idx >> 9, e = idx & 511;
    const float* src;
    if (rr < 48) {
      int gate = rr >> 4, i = rr & 15;
      src = p.Whh + ((size_t)(gate * 512 + g * 16 + i)) * 512 + e;
    } else if (rr < 96) {
      int r2 = rr - 48, gate = r2 >> 4, i = r2 & 15;
      const float* base = gate == 0 ? p.ztW : (gate == 1 ? p.rtW : p.htW);
      src = base + ((size_t)(g * 16 + i)) * 1024 + 512 + e;
    } else {
      int i = rr - 96;
      src = p.htW + ((size_t)(g * 16 + i)) * 1024 + e;
    }
    WL[rr * 520 + e] = (_Float16)(*src);
  }
  const int j = g * 16 + lr;
  const int brow = 16 * w + lk * 4;
  f32x4 hprev, zp, rp, wev;
#pragma unroll
  for (int q = 0; q < 4; ++q) {
    int b = brow + q;
    hprev[q] = p.inith[(size_t)b * 512 + j];
    zp[q] = p.ztp[(size_t)b * 512 + j];
    rp[q] = p.rtp[(size_t)b * 512 + j];
    wev[q] = p.wemb[(size_t)b * 512 + j];
    st2c(&p.hcurF[(size_t)b * 512 + j], (_Float16)hprev[q]);
  }
  const float br = p.bhh[j], bz = p.bhh[512 + j], bn = p.bhh[1024 + j];
  const float bht = p.htb[j];
  float gir[12];
#pragma unroll
  for (int q = 0; q < 4; ++q) {
    const float* git = p.gi + (size_t)(brow + q) * 1536;
    gir[q * 3 + 0] = git[j];
    gir[q * 3 + 1] = git[512 + j];
    gir[q * 3 + 2] = git[1024 + j];
  }
  __syncthreads();  // WL ready; also drains all stores/loads above
  if (l == 0) stf_mall(myflag, 1u);

  for (int t = 0; t < 64; ++t) {
    const unsigned base = 3u * (unsigned)t;
    // ---- phase 1: gates r,z,n ; h_gru ----
    poll_band(p.flags, w, l, base + 1);
    f32x4 acc1[3] = {};
    mm_mall<3>(acc1, p.hcurF, &WL[0], w, lr, lk);
    f32x4 hg;
#pragma unroll
    for (int q = 0; q < 4; ++q) {
      int b = brow + q;
      float r = sigmoidf(gir[q * 3 + 0] + br + acc1[0][q]);
      float z = sigmoidf(gir[q * 3 + 1] + bz + acc1[1][q]);
      float n = tanhf(gir[q * 3 + 2] + r * (acc1[2][q] + bn));
      float hgq = (1.f - z) * n + z * hprev[q];
      hg[q] = hgq;
      st2c(&p.hgruF[(size_t)b * 512 + j], (_Float16)hgq);
    }
    asm volatile("s_waitcnt vmcnt(0)" ::: "memory");
    if (l == 0) stf_mall(myflag, base + 2);
    // deferred: outsb stores + next-step gi prefetch (off the critical path)
#pragma unroll
    for (int q = 0; q < 4; ++q)
      p.outsb[((size_t)t * 64 + brow + q) * 512 + j] = f2bf(hg[q]);
    if (t < 63) {
      const float* git = p.gi + (size_t)(t + 1) * 64 * 1536;
#pragma unroll
      for (int q = 0; q < 4; ++q) {
        const float* gb = git + (size_t)(brow + q) * 1536;
        gir[q * 3 + 0] = gb[j];
        gir[q * 3 + 1] = gb[512 + j];
        gir[q * 3 + 2] = gb[1024 + j];
      }
    }
    // ---- phase 2: zt, rt, htB ----
    poll_band(p.flags, w, l, base + 2);
    f32x4 acc2[3] = {};
    mm_mall<3>(acc2, p.hgruF, &WL[48 * 520], w, lr, lk);
    f32x4 zt, htB;
#pragma unroll
    for (int q = 0; q < 4; ++q) {
      int b = brow + q;
      float ztq = sigmoidf(zp[q] + acc2[0][q]);
      float rtq = sigmoidf(rp[q] + acc2[1][q]);
      zt[q] = ztq;
      htB[q] = acc2[2][q];
      st2c(&p.rwF[(size_t)b * 512 + j], (_Float16)(rtq * wev[q]));
    }
    asm volatile("s_waitcnt vmcnt(0)" ::: "memory");
    if (l == 0) stf_mall(myflag, base + 3);
    // ---- phase 3: htA ; h_new ----
    poll_band(p.flags, w, l, base + 3);
    f32x4 acc3[1] = {};
    mm_mall<1>(acc3, p.rwF, &WL[96 * 520], w, lr, lk);
#pragma unroll
    for (int q = 0; q < 4; ++q) {
      int b = brow + q;
      float htl = tanhf(acc3[0][q] + htB[q] + bht);
      float hn2 = (1.f - zt[q]) * hg[q] + zt[q] * htl;
      hprev[q] = hn2;
      if (t < 63) st2c(&p.hcurF[(size_t)b * 512 + j], (_Float16)hn2);
      else p.hfin[(size_t)b * 512 + j] = hn2;
    }
    if (t < 63) {
      asm volatile("s_waitcnt vmcnt(0)" ::: "memory");
      if (l == 0) stf_mall(myflag, base + 4);
    }
  }
}

extern "C" void kernel_launch(void* const* d_in, const int* in_sizes, int n_in,
                              void* d_out, int out_size, void* d_ws, size_t ws_size,
                              hipStream_t stream) {
  const float* emb   = (const float*)d_in[0];
  const float* Wih   = (const float*)d_in[1];
  const float* Whh   = (const float*)d_in[2];
  const float* bih   = (const float*)d_in[3];
  const float* bhh   = (const float*)d_in[4];
  const float* ztW   = (const float*)d_in[5];
  const float* ztb   = (const float*)d_in[6];
  const float* rtW   = (const float*)d_in[7];
  const float* rtb   = (const float*)d_in[8];
  const float* htW   = (const float*)d_in[9];
  const float* htb   = (const float*)d_in[10];
  const float* decW  = (const float*)d_in[11];
  const float* decb  = (const float*)d_in[12];
  const float* inith = (const float*)d_in[13];
  const int* word    = (const int*)d_in[14];
  const int* seq     = (const int*)d_in[15];
  float* out = (float*)d_out;

  char* ws = (char*)d_ws;
  size_t off = 0;
  auto alloc = [&](size_t bytes) {
    size_t o = off;
    off += (bytes + 255) & ~(size_t)255;
    return o;
  };
  unsigned short* xbf   = (unsigned short*)(ws + alloc(4096ull * 512 * 2));
  unsigned short* wihbf = (unsigned short*)(ws + alloc(1536ull * 512 * 2));
  unsigned short* decbf = (unsigned short*)(ws + alloc(32000ull * 512 * 2));
  float* wemb           = (float*)(ws + alloc(64ull * 512 * 4));
  float* ztp            = (float*)(ws + alloc(64ull * 512 * 4));
  float* rtp            = (float*)(ws + alloc(64ull * 512 * 4));
  float* gi             = (float*)(ws + alloc(4096ull * 1536 * 4));
  unsigned short* outsb = (unsigned short*)(ws + alloc(4096ull * 512 * 2));
  _Float16* hcurF       = (_Float16*)(ws + alloc(64ull * 512 * 2));
  _Float16* hgruF       = (_Float16*)(ws + alloc(64ull * 512 * 2));
  _Float16* rwF         = (_Float16*)(ws + alloc(64ull * 512 * 2));
  unsigned* flags       = (unsigned*)(ws + alloc(128 * 64));

  hipLaunchKernelGGL(k_gather, dim3(4160), dim3(128), 0, stream,
                     emb, seq, word, xbf, wemb);
  hipLaunchKernelGGL(k_conv, dim3(33536), dim3(128), 0, stream,
                     Wih, decW, wihbf, decbf);
  hipLaunchKernelGGL(k_pre, dim3(256), dim3(256), 0, stream,
                     ztW, ztb, rtW, rtb, wemb, ztp, rtp);
  hipLaunchKernelGGL(k_gemm_bt, dim3(384), dim3(256), 0, stream,
                     xbf, wihbf, gi, bih, 4096, 1536, 512);
  hipMemsetAsync(flags, 0, 128 * 64, stream);
  RnnP p{Whh, ztW, rtW, htW, gi, ztp, rtp, wemb, inith, bhh, htb,
         hcurF, hgruF, rwF, outsb, out + 4096ull * 32000, flags};
  hipLaunchKernelGGL(k_rnn6, dim3(32), dim3(256), 0, stream, p);
  hipLaunchKernelGGL(k_dec, dim3(8000), dim3(256), 0, stream,
                     outsb, decbf, out, decb);
}